// Round 2
// baseline (803.704 us; speedup 1.0000x reference)
//
#include <hip/hip_runtime.h>

#define T_ 64
#define B_ 1024
#define I_ 64
#define H_ 256

typedef short bf16x8 __attribute__((ext_vector_type(8)));
typedef float f32x4 __attribute__((ext_vector_type(4)));

#define MFMA16(a, b, c) __builtin_amdgcn_mfma_f32_16x16x32_bf16((a), (b), (c), 0, 0, 0)

__device__ __forceinline__ float bf2f(unsigned short u) {
    union { unsigned int i; float f; } x;
    x.i = ((unsigned int)u) << 16;
    return x.f;
}
__device__ __forceinline__ unsigned short f2bf(float f) {
    union { float f; unsigned int i; } x;
    x.f = f;
    unsigned int u = x.i;
    unsigned int r = u + 0x7FFFu + ((u >> 16) & 1u);
    return (unsigned short)(r >> 16);
}

// ---------------------------------------------------------------------------
// Prep: split fp32 W_hh / W_ih into bf16 hi/lo pairs (hi+lo == fp32 to 2^-17).
// ---------------------------------------------------------------------------
__global__ __launch_bounds__(256) void prep_kernel(
    const float* __restrict__ Wih, const float* __restrict__ Whh,
    unsigned short* __restrict__ WihHi, unsigned short* __restrict__ WihLo,
    unsigned short* __restrict__ WhhHi, unsigned short* __restrict__ WhhLo)
{
    int idx = blockIdx.x * 256 + threadIdx.x;
    if (idx < H_ * H_) {
        float f = Whh[idx];
        unsigned short hi = f2bf(f);
        WhhHi[idx] = hi;
        WhhLo[idx] = f2bf(f - bf2f(hi));
    } else {
        int k = idx - H_ * H_;
        if (k < H_ * I_) {
            float f = Wih[k];
            unsigned short hi = f2bf(f);
            WihHi[k] = hi;
            WihLo[k] = f2bf(f - bf2f(hi));
        }
    }
}

// ---------------------------------------------------------------------------
// RNN: 64 blocks x 512 threads. Block owns 16 batch rows for all 64 steps.
// h kept fp32-exact as bf16 hi/lo pair in LDS; W and x also hi/lo-split, so
// the recurrence matches fp32 to ~2^-17. hs stored as hi+lo bf16 arrays.
// ---------------------------------------------------------------------------
__global__ __launch_bounds__(512) void rnn_kernel(
    const float* __restrict__ data,
    const float* __restrict__ h0,
    const unsigned short* __restrict__ WihHi, const unsigned short* __restrict__ WihLo,
    const unsigned short* __restrict__ WhhHi, const unsigned short* __restrict__ WhhLo,
    const float* __restrict__ bih, const float* __restrict__ bhh,
    unsigned short* __restrict__ hsHi, unsigned short* __restrict__ hsLo)
{
    __shared__ unsigned short hbuf[2][2][16 * 264];  // [buf][hi/lo][r*264+h]
    __shared__ float bsum[H_];

    const int tid  = threadIdx.x;
    const int lane = tid & 63;
    const int w    = tid >> 6;       // wave 0..7
    const int quad = lane >> 4;
    const int l15  = lane & 15;
    const int b0   = blockIdx.x * 16;

    if (tid < H_) bsum[tid] = bih[tid] + bhh[tid];
    {   // stage h0 (fp32 -> hi/lo)
        int r  = tid >> 5;            // 0..15
        int hh = (tid & 31) * 8;      // 0..248
        const float* src = h0 + (size_t)(b0 + r) * H_ + hh;
        for (int q = 0; q < 8; ++q) {
            float f = src[q];
            unsigned short hi = f2bf(f);
            hbuf[0][0][r * 264 + hh + q] = hi;
            hbuf[0][1][r * 264 + hh + q] = f2bf(f - bf2f(hi));
        }
    }
    __syncthreads();

    int cur = 0;
    const int nt0 = w * 2;           // each wave owns 2 n-tiles (of 16 cols)
    for (int t = 0; t < T_; ++t) {
        f32x4 acc[2];
        acc[0] = (f32x4){0.f, 0.f, 0.f, 0.f};
        acc[1] = (f32x4){0.f, 0.f, 0.f, 0.f};

        // h @ Whh^T : 3-term hi/lo
        for (int kc = 0; kc < 8; ++kc) {
            bf16x8 ahi = *(const bf16x8*)&hbuf[cur][0][l15 * 264 + kc * 32 + quad * 8];
            bf16x8 alo = *(const bf16x8*)&hbuf[cur][1][l15 * 264 + kc * 32 + quad * 8];
            for (int it = 0; it < 2; ++it) {
                int n = (nt0 + it) * 16 + l15;
                bf16x8 whi = *(const bf16x8*)(WhhHi + (size_t)n * H_ + kc * 32 + quad * 8);
                bf16x8 wlo = *(const bf16x8*)(WhhLo + (size_t)n * H_ + kc * 32 + quad * 8);
                acc[it] = MFMA16(ahi, whi, acc[it]);
                acc[it] = MFMA16(ahi, wlo, acc[it]);
                acc[it] = MFMA16(alo, whi, acc[it]);
            }
        }
        // x @ Wih^T : split x on the fly, 3-term
        for (int kx = 0; kx < 2; ++kx) {
            const float* dp = data + ((size_t)t * B_ + b0 + l15) * I_ + kx * 32 + quad * 8;
            bf16x8 xhi, xlo;
            for (int q = 0; q < 8; ++q) {
                float f = dp[q];
                unsigned short h1 = f2bf(f);
                xhi[q] = (short)h1;
                xlo[q] = (short)f2bf(f - bf2f(h1));
            }
            for (int it = 0; it < 2; ++it) {
                int n = (nt0 + it) * 16 + l15;
                bf16x8 whi = *(const bf16x8*)(WihHi + (size_t)n * I_ + kx * 32 + quad * 8);
                bf16x8 wlo = *(const bf16x8*)(WihLo + (size_t)n * I_ + kx * 32 + quad * 8);
                acc[it] = MFMA16(xhi, whi, acc[it]);
                acc[it] = MFMA16(xhi, wlo, acc[it]);
                acc[it] = MFMA16(xlo, whi, acc[it]);
            }
        }

        int nxt = cur ^ 1;
        for (int it = 0; it < 2; ++it) {
            int h = (nt0 + it) * 16 + l15;
            float bs = bsum[h];
            for (int reg = 0; reg < 4; ++reg) {
                int r = quad * 4 + reg;                 // C/D: row = quad*4+reg, col = l15
                float v = acc[it][reg] + bs;
                v = fmaxf(v, 0.f);
                unsigned short hi = f2bf(v);
                unsigned short lo = f2bf(v - bf2f(hi));
                hbuf[nxt][0][r * 264 + h] = hi;
                hbuf[nxt][1][r * 264 + h] = lo;
                size_t gidx = ((size_t)t * B_ + b0 + r) * H_ + h;
                hsHi[gidx] = hi;
                hsLo[gidx] = lo;
            }
        }
        __syncthreads();
        cur = nxt;
    }
}

// ---------------------------------------------------------------------------
// Attention + pred: 1024 blocks (one per batch b) x 256 threads (4 waves).
// Scores use hi/lo 3-term MFMA (fp32-accurate logits); softmax fp32;
// PV and pred in single-bf16 (rel 2e-3, well under 2% threshold).
// ---------------------------------------------------------------------------
__global__ __launch_bounds__(256) void attn_kernel(
    const unsigned short* __restrict__ hsHi,
    const unsigned short* __restrict__ hsLo,
    const int* __restrict__ nti,
    const float* __restrict__ Wlin,
    const float* __restrict__ blin,
    float* __restrict__ outPred,
    float* __restrict__ outAttn)
{
    __shared__ unsigned short GpH[32 * 264];   // [jslot*16+n][h], rows 9..15/25..31 zero
    __shared__ unsigned short GpL[32 * 264];
    __shared__ unsigned short GpT[256 * 40];   // [h][k=jslot*16+n], cols 9..15/25..31 zero
    __shared__ unsigned short Pb[64 * 40];     // [i][k] masked P
    __shared__ float wl[2 * H_];
    __shared__ float predc[64];
    __shared__ int   sidx[9];
    __shared__ float blin_s;

    const int tid  = threadIdx.x;
    const int lane = tid & 63;
    const int w    = tid >> 6;
    const int quad = lane >> 4;
    const int l15  = lane & 15;
    const int b    = blockIdx.x;

    for (int e = tid; e < 2 * H_; e += 256) wl[e] = Wlin[e];
    if (tid == 0) blin_s = blin[0];
    if (tid < 9) sidx[tid] = nti[b * 9 + tid];
    for (int e = tid; e < 14 * 264; e += 256) {       // zero pad rows (n=9..15)
        int rr = e / 264, c = e % 264;
        int row = (rr < 7) ? (9 + rr) : (18 + rr);
        GpH[row * 264 + c] = 0;
        GpL[row * 264 + c] = 0;
    }
    for (int e = tid; e < 256 * 14; e += 256) {       // zero GpT pad cols
        int h = e / 14, q = e % 14;
        int k = (q < 7) ? (9 + q) : (18 + q);
        GpT[h * 40 + k] = 0;
    }

    // Hd hi/lo A-fragments for this wave's 16 i-rows, registers for all 64 j
    bf16x8 af[8], afl[8];
    {
        size_t base = ((size_t)(w * 16 + l15) * B_ + b) * H_;
        for (int kc = 0; kc < 8; ++kc) {
            af[kc]  = *(const bf16x8*)(hsHi + base + kc * 32 + quad * 8);
            afl[kc] = *(const bf16x8*)(hsLo + base + kc * 32 + quad * 8);
        }
    }
    f32x4 acc[16];
    for (int nt = 0; nt < 16; ++nt) acc[nt] = (f32x4){0.f, 0.f, 0.f, 0.f};
    __syncthreads();

    for (int p = 0; p < 32; ++p) {
        // --- stage gathered rows for j = 2p, 2p+1 ---
        for (int rr = w; rr < 18; rr += 4) {
            int jslot = rr / 9;
            int n = rr % 9;
            int j = 2 * p + jslot;
            int bi = sidx[n];
            ushort4 vh, vl;
            if (bi < B_) {
                size_t base = ((size_t)j * B_ + bi) * H_;
                vh = ((const ushort4*)(hsHi + base))[lane];
                vl = ((const ushort4*)(hsLo + base))[lane];
            } else {
                vh.x = vh.y = vh.z = vh.w = 0;
                vl.x = vl.y = vl.z = vl.w = 0;
            }
            *(ushort4*)&GpH[(jslot * 16 + n) * 264 + lane * 4] = vh;
            *(ushort4*)&GpL[(jslot * 16 + n) * 264 + lane * 4] = vl;
            unsigned short vv[4] = {vh.x, vh.y, vh.z, vh.w};
            for (int q = 0; q < 4; ++q)
                GpT[(lane * 4 + q) * 40 + jslot * 16 + n] = vv[q];
        }
        __syncthreads();

        // --- scores (3-term hi/lo) + softmax + attn + P ---
        for (int jslot = 0; jslot < 2; ++jslot) {
            int j = 2 * p + jslot;
            f32x4 s = (f32x4){0.f, 0.f, 0.f, 0.f};
            for (int kc = 0; kc < 8; ++kc) {
                bf16x8 bh = *(const bf16x8*)&GpH[(jslot * 16 + l15) * 264 + kc * 32 + quad * 8];
                bf16x8 bl = *(const bf16x8*)&GpL[(jslot * 16 + l15) * 264 + kc * 32 + quad * 8];
                s = MFMA16(af[kc],  bh, s);
                s = MFMA16(afl[kc], bh, s);
                s = MFMA16(af[kc],  bl, s);
            }
            for (int reg = 0; reg < 4; ++reg) {
                int i = w * 16 + quad * 4 + reg;
                float v = s[reg];
                float vm = (l15 <= 8) ? v : -1e30f;
                for (int m = 8; m >= 1; m >>= 1) vm = fmaxf(vm, __shfl_xor(vm, m, 16));
                float e = (l15 <= 8) ? __expf(v - vm) : 0.f;
                float su = e;
                for (int m = 8; m >= 1; m >>= 1) su += __shfl_xor(su, m, 16);
                float pr = e / su;
                if (l15 <= 8)
                    outAttn[(((size_t)i * T_ + j) * B_ + b) * 9 + l15] = pr;
                unsigned short pm = (j < i && l15 <= 8) ? f2bf(pr) : (unsigned short)0;
                Pb[i * 40 + jslot * 16 + l15] = pm;
            }
        }
        __syncthreads();

        // --- c += P_masked @ G (K = 32 = this j-pair) ---
        {
            bf16x8 afp = *(const bf16x8*)&Pb[(w * 16 + l15) * 40 + quad * 8];
            for (int nt = 0; nt < 16; ++nt) {
                bf16x8 bfg = *(const bf16x8*)&GpT[(nt * 16 + l15) * 40 + quad * 8];
                acc[nt] = MFMA16(afp, bfg, acc[nt]);
            }
        }
        __syncthreads();   // protect Gp/GpT before next stage
    }

    // --- fused pred epilogue ---
    float hw1 = 0.f, hw2 = 0.f;    // hs[i].W1, hs[i].W2 partials (i = w*16 + l15)
    for (int kc = 0; kc < 8; ++kc) {
        for (int jj = 0; jj < 8; ++jj) {
            float hv = bf2f((unsigned short)af[kc][jj]) + bf2f((unsigned short)afl[kc][jj]);
            int h = kc * 32 + quad * 8 + jj;
            hw1 += hv * wl[h];
            hw2 += hv * wl[H_ + h];
        }
    }
    hw1 += __shfl_xor(hw1, 16, 64); hw1 += __shfl_xor(hw1, 32, 64);
    hw2 += __shfl_xor(hw2, 16, 64); hw2 += __shfl_xor(hw2, 32, 64);

    for (int reg = 0; reg < 4; ++reg) {            // c[i].W1 from accumulators
        float cp = 0.f;
        for (int nt = 0; nt < 16; ++nt)
            cp += acc[nt][reg] * wl[nt * 16 + l15];
        for (int m = 8; m >= 1; m >>= 1) cp += __shfl_xor(cp, m, 16);
        if (l15 == 0) predc[w * 16 + quad * 4 + reg] = cp;
    }
    __syncthreads();
    if (lane < 16) {
        int i = w * 16 + lane;
        // c[0] = hs[0] (c_rest[0]=0 by mask), so use hs0.W1 for i==0
        float v = predc[i] + hw2 + ((i == 0) ? hw1 : 0.f) + blin_s;
        v = fmaxf(v, 0.f);
        outPred[(size_t)i * B_ + b] = v;
    }
}

extern "C" void kernel_launch(void* const* d_in, const int* in_sizes, int n_in,
                              void* d_out, int out_size, void* d_ws, size_t ws_size,
                              hipStream_t stream) {
    (void)in_sizes; (void)n_in; (void)out_size; (void)ws_size;
    const float* data = (const float*)d_in[0];
    const int*   nti  = (const int*)d_in[1];
    // d_in[2] haven_flag == 0 always
    const float* h0   = (const float*)d_in[3];
    const float* Wih  = (const float*)d_in[4];
    const float* Whh  = (const float*)d_in[5];
    const float* bih  = (const float*)d_in[6];
    const float* bhh  = (const float*)d_in[7];
    const float* Wlin = (const float*)d_in[8];
    const float* blin = (const float*)d_in[9];

    unsigned short* ws = (unsigned short*)d_ws;
    unsigned short* hsHi  = ws;                                   // 16.7M ushort
    unsigned short* hsLo  = ws + (size_t)T_ * B_ * H_;            // 16.7M ushort
    unsigned short* WhhHi = ws + (size_t)2 * T_ * B_ * H_;
    unsigned short* WhhLo = WhhHi + H_ * H_;
    unsigned short* WihHi = WhhLo + H_ * H_;
    unsigned short* WihLo = WihHi + H_ * I_;

    float* outPred = (float*)d_out;                               // (T,B,1)
    float* outAttn = (float*)d_out + (size_t)T_ * B_;             // (T,T,B,9)

    prep_kernel<<<dim3(320), dim3(256), 0, stream>>>(Wih, Whh, WihHi, WihLo, WhhHi, WhhLo);
    rnn_kernel<<<dim3(64), dim3(512), 0, stream>>>(data, h0, WihHi, WihLo, WhhHi, WhhLo,
                                                   bih, bhh, hsHi, hsLo);
    attn_kernel<<<dim3(1024), dim3(256), 0, stream>>>(hsHi, hsLo, nti, Wlin, blin,
                                                      outPred, outAttn);
}

// Round 3
// 620.911 us; speedup vs baseline: 1.2944x; 1.2944x over previous
//
#include <hip/hip_runtime.h>

#define T_ 64
#define B_ 1024
#define I_ 64
#define H_ 256

typedef short bf16x8 __attribute__((ext_vector_type(8)));
typedef float f32x4 __attribute__((ext_vector_type(4)));

#define MFMA16(a, b, c) __builtin_amdgcn_mfma_f32_16x16x32_bf16((a), (b), (c), 0, 0, 0)

__device__ __forceinline__ float bf2f(unsigned short u) {
    union { unsigned int i; float f; } x;
    x.i = ((unsigned int)u) << 16;
    return x.f;
}
__device__ __forceinline__ unsigned short f2bf(float f) {
    union { float f; unsigned int i; } x;
    x.f = f;
    unsigned int u = x.i;
    unsigned int r = u + 0x7FFFu + ((u >> 16) & 1u);
    return (unsigned short)(r >> 16);
}
__device__ __forceinline__ void split8(const float* p, bf16x8& hi, bf16x8& lo) {
    for (int q = 0; q < 8; ++q) {
        float f = p[q];
        unsigned short h1 = f2bf(f);
        hi[q] = (short)h1;
        lo[q] = (short)f2bf(f - bf2f(h1));
    }
}

// ---------------------------------------------------------------------------
// RNN: 64 blocks x 512 threads (8 waves), 16 batch rows/block for 64 steps.
// W_hh/W_ih hi/lo pairs live in REGISTERS (loaded once, ~160 VGPR) so the
// K-loop has zero global W traffic. h fp32-exact as bf16 hi/lo in LDS.
// hs stores staged through LDS for coalesced 16B/lane global writes.
// ---------------------------------------------------------------------------
__global__ __launch_bounds__(512, 2) void rnn_kernel(
    const float* __restrict__ data,
    const float* __restrict__ h0,
    const float* __restrict__ Wih, const float* __restrict__ Whh,
    const float* __restrict__ bih, const float* __restrict__ bhh,
    unsigned short* __restrict__ hsHi, unsigned short* __restrict__ hsLo)
{
    __shared__ unsigned short hbuf[2][2][16 * 264];  // [buf][hi/lo][r*264+h]
    __shared__ float bsum[H_];

    const int tid  = threadIdx.x;
    const int lane = tid & 63;
    const int w    = tid >> 6;       // wave 0..7
    const int quad = lane >> 4;
    const int l15  = lane & 15;
    const int b0   = blockIdx.x * 16;

    // W in registers: wave w owns n-tiles 2w, 2w+1 (n = tile*16 + l15)
    bf16x8 whhH[2][8], whhL[2][8], wihH[2][2], wihL[2][2];
    for (int it = 0; it < 2; ++it) {
        int n = (w * 2 + it) * 16 + l15;
        for (int kc = 0; kc < 8; ++kc)
            split8(Whh + (size_t)n * H_ + kc * 32 + quad * 8, whhH[it][kc], whhL[it][kc]);
        for (int kx = 0; kx < 2; ++kx)
            split8(Wih + (size_t)n * I_ + kx * 32 + quad * 8, wihH[it][kx], wihL[it][kx]);
    }

    if (tid < H_) bsum[tid] = bih[tid] + bhh[tid];
    {   // stage h0 (fp32 -> hi/lo)
        int r  = tid >> 5;            // 0..15
        int hh = (tid & 31) * 8;      // 0..248
        const float* src = h0 + (size_t)(b0 + r) * H_ + hh;
        for (int q = 0; q < 8; ++q) {
            float f = src[q];
            unsigned short hi = f2bf(f);
            hbuf[0][0][r * 264 + hh + q] = hi;
            hbuf[0][1][r * 264 + hh + q] = f2bf(f - bf2f(hi));
        }
    }
    __syncthreads();

    int cur = 0;
    for (int t = 0; t < T_; ++t) {
        f32x4 acc[2];
        acc[0] = (f32x4){0.f, 0.f, 0.f, 0.f};
        acc[1] = (f32x4){0.f, 0.f, 0.f, 0.f};

        // x @ Wih^T first (global x load latency overlaps following MFMAs)
        for (int kx = 0; kx < 2; ++kx) {
            bf16x8 xhi, xlo;
            split8(data + ((size_t)t * B_ + b0 + l15) * I_ + kx * 32 + quad * 8, xhi, xlo);
            for (int it = 0; it < 2; ++it) {
                acc[it] = MFMA16(xhi, wihH[it][kx], acc[it]);
                acc[it] = MFMA16(xhi, wihL[it][kx], acc[it]);
                acc[it] = MFMA16(xlo, wihH[it][kx], acc[it]);
            }
        }
        // h @ Whh^T : 3-term hi/lo, W from registers
        for (int kc = 0; kc < 8; ++kc) {
            bf16x8 ahi = *(const bf16x8*)&hbuf[cur][0][l15 * 264 + kc * 32 + quad * 8];
            bf16x8 alo = *(const bf16x8*)&hbuf[cur][1][l15 * 264 + kc * 32 + quad * 8];
            for (int it = 0; it < 2; ++it) {
                acc[it] = MFMA16(ahi, whhH[it][kc], acc[it]);
                acc[it] = MFMA16(ahi, whhL[it][kc], acc[it]);
                acc[it] = MFMA16(alo, whhH[it][kc], acc[it]);
            }
        }

        int nxt = cur ^ 1;
        for (int it = 0; it < 2; ++it) {
            int h = (w * 2 + it) * 16 + l15;
            float bs = bsum[h];
            for (int reg = 0; reg < 4; ++reg) {
                int r = quad * 4 + reg;                 // C/D: row = quad*4+reg, col = l15
                float v = acc[it][reg] + bs;
                v = fmaxf(v, 0.f);
                unsigned short hi = f2bf(v);
                unsigned short lo = f2bf(v - bf2f(hi));
                hbuf[nxt][0][r * 264 + h] = hi;
                hbuf[nxt][1][r * 264 + h] = lo;
            }
        }
        __syncthreads();
        // coalesced hs store from LDS: 512 thr x 16B per array
        {
            int r  = tid >> 5;
            int hc = (tid & 31) * 8;
            size_t g = ((size_t)t * B_ + b0 + r) * H_ + hc;
            *(bf16x8*)(hsHi + g) = *(const bf16x8*)&hbuf[nxt][0][r * 264 + hc];
            *(bf16x8*)(hsLo + g) = *(const bf16x8*)&hbuf[nxt][1][r * 264 + hc];
        }
        cur = nxt;
    }
}

// ---------------------------------------------------------------------------
// Attention + pred: 1024 blocks (one per b) x 256 threads (4 waves).
// Scores: A = gathered rows (LDS), B = Hd register fragments -> S[n][i];
// softmax over n = 4 in-lane regs + 2 shuffles. PV K-dim interleaved
// (k' = 2n + jslot) so the LDS transpose is ushort2 stores (4x fewer).
// ---------------------------------------------------------------------------
__global__ __launch_bounds__(256) void attn_kernel(
    const unsigned short* __restrict__ hsHi,
    const unsigned short* __restrict__ hsLo,
    const int* __restrict__ nti,
    const float* __restrict__ Wlin,
    const float* __restrict__ blin,
    float* __restrict__ outPred,
    float* __restrict__ outAttn)
{
    __shared__ unsigned short GpH[32 * 264];   // [jslot*16+n][h], rows 9..15/25..31 zero
    __shared__ unsigned short GpL[32 * 264];
    __shared__ unsigned short GpT[256 * 40];   // [h][k'=2n+jslot], cols 18..31 zero
    __shared__ unsigned short Pb[64 * 40];     // [i][k'] masked P
    __shared__ float wl[2 * H_];
    __shared__ float predc[64];
    __shared__ int   sidx[9];
    __shared__ float blin_s;

    const int tid  = threadIdx.x;
    const int lane = tid & 63;
    const int w    = tid >> 6;
    const int quad = lane >> 4;
    const int l15  = lane & 15;
    const int b    = blockIdx.x;

    for (int e = tid; e < 2 * H_; e += 256) wl[e] = Wlin[e];
    if (tid == 0) blin_s = blin[0];
    if (tid < 9) sidx[tid] = nti[b * 9 + tid];
    for (int e = tid; e < 14 * 264; e += 256) {       // zero Gp pad rows (n=9..15)
        int rr = e / 264, c = e % 264;
        int row = (rr < 7) ? (9 + rr) : (18 + rr);
        GpH[row * 264 + c] = 0;
        GpL[row * 264 + c] = 0;
    }
    for (int e = tid; e < 256 * 14; e += 256) {       // zero GpT cols k'=18..31
        int h = e / 14, c = 18 + e % 14;
        GpT[h * 40 + c] = 0;
    }
    for (int e = tid; e < 64 * 14; e += 256) {        // zero Pb cols k'=18..31
        int i = e / 14, c = 18 + e % 14;
        Pb[i * 40 + c] = 0;
    }

    // Hd hi/lo B-fragments (lane=col=i, regs=k=h) for this wave's 16 i-rows
    bf16x8 af[8], afl[8];
    {
        size_t base = ((size_t)(w * 16 + l15) * B_ + b) * H_;
        for (int kc = 0; kc < 8; ++kc) {
            af[kc]  = *(const bf16x8*)(hsHi + base + kc * 32 + quad * 8);
            afl[kc] = *(const bf16x8*)(hsLo + base + kc * 32 + quad * 8);
        }
    }
    f32x4 acc[16];
    for (int nt = 0; nt < 16; ++nt) acc[nt] = (f32x4){0.f, 0.f, 0.f, 0.f};
    __syncthreads();

    for (int p = 0; p < 32; ++p) {
        int j0 = 2 * p;
        // --- gather rows n=0..8, both jslots per thread-row ---
        for (int n = w; n < 9; n += 4) {
            int bi = sidx[n];
            ushort4 vh0, vl0, vh1, vl1;
            if (bi < B_) {
                size_t base0 = ((size_t)j0 * B_ + bi) * H_;
                size_t base1 = base0 + (size_t)B_ * H_;
                vh0 = ((const ushort4*)(hsHi + base0))[lane];
                vl0 = ((const ushort4*)(hsLo + base0))[lane];
                vh1 = ((const ushort4*)(hsHi + base1))[lane];
                vl1 = ((const ushort4*)(hsLo + base1))[lane];
            } else {
                vh0.x=vh0.y=vh0.z=vh0.w=0; vl0.x=vl0.y=vl0.z=vl0.w=0;
                vh1.x=vh1.y=vh1.z=vh1.w=0; vl1.x=vl1.y=vl1.z=vl1.w=0;
            }
            *(ushort4*)&GpH[n * 264 + lane * 4]        = vh0;
            *(ushort4*)&GpL[n * 264 + lane * 4]        = vl0;
            *(ushort4*)&GpH[(16 + n) * 264 + lane * 4] = vh1;
            *(ushort4*)&GpL[(16 + n) * 264 + lane * 4] = vl1;
            unsigned short h0v[4] = {vh0.x, vh0.y, vh0.z, vh0.w};
            unsigned short h1v[4] = {vh1.x, vh1.y, vh1.z, vh1.w};
            for (int q = 0; q < 4; ++q) {
                ushort2 pr2; pr2.x = h0v[q]; pr2.y = h1v[q];
                *(ushort2*)&GpT[(lane * 4 + q) * 40 + 2 * n] = pr2;
            }
        }
        __syncthreads();

        // --- scores S[n][i] (A = G rows from LDS, B = Hd regs), softmax, P ---
        for (int jslot = 0; jslot < 2; ++jslot) {
            int j = j0 + jslot;
            f32x4 s = (f32x4){0.f, 0.f, 0.f, 0.f};
            for (int kc = 0; kc < 8; ++kc) {
                bf16x8 aH = *(const bf16x8*)&GpH[(jslot * 16 + l15) * 264 + kc * 32 + quad * 8];
                bf16x8 aL = *(const bf16x8*)&GpL[(jslot * 16 + l15) * 264 + kc * 32 + quad * 8];
                s = MFMA16(aH, af[kc],  s);
                s = MFMA16(aH, afl[kc], s);
                s = MFMA16(aL, af[kc],  s);
            }
            // D[row=n=quad*4+reg][col=i=l15]: softmax over n = regs + quad lanes
            int i = w * 16 + l15;
            int nvalid = (quad < 2) ? 4 : ((quad == 2) ? 1 : 0);
            float mp = -1e30f;
            for (int r = 0; r < 4; ++r) if (r < nvalid) mp = fmaxf(mp, s[r]);
            mp = fmaxf(mp, __shfl_xor(mp, 16, 64));
            mp = fmaxf(mp, __shfl_xor(mp, 32, 64));
            float e[4], sp = 0.f;
            for (int r = 0; r < 4; ++r) {
                e[r] = (r < nvalid) ? __expf(s[r] - mp) : 0.f;
                sp += e[r];
            }
            sp += __shfl_xor(sp, 16, 64);
            sp += __shfl_xor(sp, 32, 64);
            float inv = 1.f / sp;
            for (int r = 0; r < 4; ++r) {
                if (r < nvalid) {
                    int n = quad * 4 + r;
                    float pr = e[r] * inv;
                    outAttn[(((size_t)i * T_ + j) * B_ + b) * 9 + n] = pr;
                    unsigned short pm = (j < i) ? f2bf(pr) : (unsigned short)0;
                    Pb[i * 40 + 2 * n + jslot] = pm;
                }
            }
        }
        // Pb rows are wave-local; GpT was barrier-protected — no barrier here.

        // --- c += P @ G (K=32, k'-interleaved) ---
        {
            bf16x8 afp = *(const bf16x8*)&Pb[(w * 16 + l15) * 40 + quad * 8];
            for (int nt = 0; nt < 16; ++nt) {
                bf16x8 bfg = *(const bf16x8*)&GpT[(nt * 16 + l15) * 40 + quad * 8];
                acc[nt] = MFMA16(afp, bfg, acc[nt]);
            }
        }
        __syncthreads();   // protect Gp/GpT before next gather
    }

    // --- fused pred epilogue (acc[nt][reg] = c[i=w*16+quad*4+reg][h=nt*16+l15]) ---
    float hw1 = 0.f, hw2 = 0.f;    // hs[i].W1, hs[i].W2 (i = w*16 + l15)
    for (int kc = 0; kc < 8; ++kc) {
        for (int jj = 0; jj < 8; ++jj) {
            float hv = bf2f((unsigned short)af[kc][jj]) + bf2f((unsigned short)afl[kc][jj]);
            int h = kc * 32 + quad * 8 + jj;
            hw1 += hv * wl[h];
            hw2 += hv * wl[H_ + h];
        }
    }
    hw1 += __shfl_xor(hw1, 16, 64); hw1 += __shfl_xor(hw1, 32, 64);
    hw2 += __shfl_xor(hw2, 16, 64); hw2 += __shfl_xor(hw2, 32, 64);

    for (int reg = 0; reg < 4; ++reg) {            // c[i].W1 from accumulators
        float cp = 0.f;
        for (int nt = 0; nt < 16; ++nt)
            cp += acc[nt][reg] * wl[nt * 16 + l15];
        for (int m = 8; m >= 1; m >>= 1) cp += __shfl_xor(cp, m, 16);
        if (l15 == 0) predc[w * 16 + quad * 4 + reg] = cp;
    }
    __syncthreads();
    if (lane < 16) {
        int i = w * 16 + lane;
        float v = predc[i] + hw2 + ((i == 0) ? hw1 : 0.f) + blin_s;
        v = fmaxf(v, 0.f);
        outPred[(size_t)i * B_ + b] = v;
    }
}

extern "C" void kernel_launch(void* const* d_in, const int* in_sizes, int n_in,
                              void* d_out, int out_size, void* d_ws, size_t ws_size,
                              hipStream_t stream) {
    (void)in_sizes; (void)n_in; (void)out_size; (void)ws_size;
    const float* data = (const float*)d_in[0];
    const int*   nti  = (const int*)d_in[1];
    // d_in[2] haven_flag == 0 always
    const float* h0   = (const float*)d_in[3];
    const float* Wih  = (const float*)d_in[4];
    const float* Whh  = (const float*)d_in[5];
    const float* bih  = (const float*)d_in[6];
    const float* bhh  = (const float*)d_in[7];
    const float* Wlin = (const float*)d_in[8];
    const float* blin = (const float*)d_in[9];

    unsigned short* ws = (unsigned short*)d_ws;
    unsigned short* hsHi = ws;                                    // T*B*H
    unsigned short* hsLo = ws + (size_t)T_ * B_ * H_;             // T*B*H

    float* outPred = (float*)d_out;                               // (T,B,1)
    float* outAttn = (float*)d_out + (size_t)T_ * B_;             // (T,T,B,9)

    rnn_kernel<<<dim3(64), dim3(512), 0, stream>>>(data, h0, Wih, Whh, bih, bhh, hsHi, hsLo);
    attn_kernel<<<dim3(1024), dim3(256), 0, stream>>>(hsHi, hsLo, nti, Wlin, blin,
                                                      outPred, outAttn);
}